// Round 2
// baseline (129.612 us; speedup 1.0000x reference)
//
#include <hip/hip_runtime.h>

// 3x3 conv, stride 1, dilation 1, zero pad 1, on HxW fp32, 9 weights + bias.
// Each thread produces 4 consecutive output columns (float4 store).
// Per input row contributing: one aligned float4 load + 2 scalar edge loads.

#define H 4096
#define W 4096
#define COLS_PER_THREAD 4
#define BLOCK 256

__global__ __launch_bounds__(BLOCK) void conv3x3_kernel(
    const float* __restrict__ x, const float* __restrict__ w9,
    const float* __restrict__ bias, float* __restrict__ out) {
    const int c = (blockIdx.x * BLOCK + threadIdx.x) * COLS_PER_THREAD;
    const int r = blockIdx.y;
    if (c >= W || r >= H) return;

    const float b = bias[0];
    float acc0 = b, acc1 = b, acc2 = b, acc3 = b;

#pragma unroll
    for (int dr = 0; dr < 3; ++dr) {
        const int rr = r + dr - 1;
        if (rr < 0 || rr >= H) continue;
        const float* row = x + (size_t)rr * W + c;
        const float4 v = *(const float4*)row;
        const float left  = (c > 0)       ? row[-1] : 0.0f;
        const float right = (c + 4 < W)   ? row[4]  : 0.0f;
        const float w0 = w9[dr * 3 + 0];
        const float w1 = w9[dr * 3 + 1];
        const float w2 = w9[dr * 3 + 2];
        acc0 = fmaf(w0, left, fmaf(w1, v.x, fmaf(w2, v.y, acc0)));
        acc1 = fmaf(w0, v.x,  fmaf(w1, v.y, fmaf(w2, v.z, acc1)));
        acc2 = fmaf(w0, v.y,  fmaf(w1, v.z, fmaf(w2, v.w, acc2)));
        acc3 = fmaf(w0, v.z,  fmaf(w1, v.w, fmaf(w2, right, acc3)));
    }

    float4 o = make_float4(acc0, acc1, acc2, acc3);
    *(float4*)(out + (size_t)r * W + c) = o;
}

extern "C" void kernel_launch(void* const* d_in, const int* in_sizes, int n_in,
                              void* d_out, int out_size, void* d_ws, size_t ws_size,
                              hipStream_t stream) {
    const float* x = (const float*)d_in[0];
    const float* w = (const float*)d_in[1];
    const float* bias = (const float*)d_in[2];
    float* out = (float*)d_out;

    dim3 block(BLOCK, 1, 1);
    dim3 grid(W / (BLOCK * COLS_PER_THREAD), H, 1);
    conv3x3_kernel<<<grid, block, 0, stream>>>(x, w, bias, out);
}

// Round 3
// 121.719 us; speedup vs baseline: 1.0649x; 1.0649x over previous
//
#include <hip/hip_runtime.h>

// 3x3 conv, stride 1, dilation 1, zero pad 1, on HxW fp32, 9 weights + bias.
// Each thread computes a 4-row x 4-col output tile. Loads 6 input rows
// (float4 + 2 edge scalars each) and reuses them across the 4 output rows:
// halves VMEM instruction count per output byte vs 1-row version and gives
// 6 independent row loads in flight (MLP).

#define H 4096
#define W 4096
#define COLS_PER_THREAD 4
#define ROWS_PER_THREAD 4
#define BLOCK 256

__global__ __launch_bounds__(BLOCK) void conv3x3_kernel(
    const float* __restrict__ x, const float* __restrict__ w9,
    const float* __restrict__ bias, float* __restrict__ out) {
    const int c = (blockIdx.x * BLOCK + threadIdx.x) * COLS_PER_THREAD;
    const int r0 = blockIdx.y * ROWS_PER_THREAD;
    if (c >= W || r0 >= H) return;

    // Weights: uniform address -> compiler emits scalar loads, negligible.
    float wv[9];
#pragma unroll
    for (int i = 0; i < 9; ++i) wv[i] = w9[i];
    const float b = bias[0];

    // Load all 6 contributing input rows first (maximize loads in flight).
    float4 v[6];
    float lf[6], rt[6];
#pragma unroll
    for (int i = 0; i < 6; ++i) {
        const int rr = r0 + i - 1;
        if (rr >= 0 && rr < H) {
            const float* row = x + (size_t)rr * W + c;
            v[i] = *(const float4*)row;
            lf[i] = (c > 0) ? row[-1] : 0.0f;
            rt[i] = (c + 4 < W) ? row[4] : 0.0f;
        } else {
            v[i] = make_float4(0.f, 0.f, 0.f, 0.f);
            lf[i] = 0.0f;
            rt[i] = 0.0f;
        }
    }

    float4 acc[4];
#pragma unroll
    for (int j = 0; j < 4; ++j) acc[j] = make_float4(b, b, b, b);

#pragma unroll
    for (int j = 0; j < 4; ++j) {
#pragma unroll
        for (int dr = 0; dr < 3; ++dr) {
            const int i = j + dr;  // input row index within v[]
            const float w0 = wv[dr * 3 + 0];
            const float w1 = wv[dr * 3 + 1];
            const float w2 = wv[dr * 3 + 2];
            acc[j].x = fmaf(w0, lf[i],  fmaf(w1, v[i].x, fmaf(w2, v[i].y, acc[j].x)));
            acc[j].y = fmaf(w0, v[i].x, fmaf(w1, v[i].y, fmaf(w2, v[i].z, acc[j].y)));
            acc[j].z = fmaf(w0, v[i].y, fmaf(w1, v[i].z, fmaf(w2, v[i].w, acc[j].z)));
            acc[j].w = fmaf(w0, v[i].z, fmaf(w1, v[i].w, fmaf(w2, rt[i],  acc[j].w)));
        }
    }

#pragma unroll
    for (int j = 0; j < 4; ++j) {
        *(float4*)(out + (size_t)(r0 + j) * W + c) = acc[j];
    }
}

extern "C" void kernel_launch(void* const* d_in, const int* in_sizes, int n_in,
                              void* d_out, int out_size, void* d_ws, size_t ws_size,
                              hipStream_t stream) {
    const float* x = (const float*)d_in[0];
    const float* w = (const float*)d_in[1];
    const float* bias = (const float*)d_in[2];
    float* out = (float*)d_out;

    dim3 block(BLOCK, 1, 1);
    dim3 grid(W / (BLOCK * COLS_PER_THREAD), H / ROWS_PER_THREAD, 1);
    conv3x3_kernel<<<grid, block, 0, stream>>>(x, w, bias, out);
}